// Round 3
// baseline (206.630 us; speedup 1.0000x reference)
//
#include <hip/hip_runtime.h>
#include <hip/hip_bf16.h>

#define DEVI __device__ __forceinline__

typedef __attribute__((ext_vector_type(8))) short bf16x8_t;
typedef __attribute__((ext_vector_type(4))) float f32x4_t;
typedef __attribute__((ext_vector_type(4))) short s16x4_t;
typedef __attribute__((ext_vector_type(2))) unsigned int u32x2_t;

#define QSCALE 0.18033688011112043f   /* 0.125 * log2(e): softmax in exp2 domain */
#define EXP2F(x) __builtin_amdgcn_exp2f(x)

// fp32 -> bf16 bits, round-to-nearest-even
static DEVI unsigned short f2b_bits(float f) {
    unsigned int u = __float_as_uint(f);
    unsigned int r = (u + 0x7fffu + ((u >> 16) & 1u)) >> 16;
    return (unsigned short)r;
}

static DEVI unsigned int cvtpk_bf16(float lo, float hi) {
    unsigned int r;
    asm("v_cvt_pk_bf16_f32 %0, %1, %2" : "=v"(r) : "v"(lo), "v"(hi));
    return r;
}

static DEVI void gload16(const short* g, short* l) {
    __builtin_amdgcn_global_load_lds((const __attribute__((address_space(1))) void*)g,
                                     (__attribute__((address_space(3))) void*)l, 16, 0, 0);
}

// ---------------- cast fp32 -> bf16 ----------------
__global__ void cast_bf16_k(const float* __restrict__ in, short* __restrict__ out, long n) {
    long i = ((long)blockIdx.x * blockDim.x + threadIdx.x) * 4;
    if (i >= n) return;
    const float4 v = *(const float4*)(in + i);
    s16x4_t o;
    o[0] = (short)f2b_bits(v.x); o[1] = (short)f2b_bits(v.y);
    o[2] = (short)f2b_bits(v.z); o[3] = (short)f2b_bits(v.w);
    *(s16x4_t*)(out + i) = o;
}

// ---------------- transpose + cast: w[K][N] fp32 -> wT[N][K] bf16 ----------------
__global__ void transpose_cast(const float* __restrict__ w, short* __restrict__ wT,
                               int K, int N) {
    __shared__ float tile[32][33];
    const int n0 = blockIdx.x * 32, k0 = blockIdx.y * 32;
    const int tx = threadIdx.x, ty = threadIdx.y;
#pragma unroll
    for (int i = 0; i < 4; ++i)
        tile[ty + 8 * i][tx] = w[(long)(k0 + ty + 8 * i) * N + n0 + tx];
    __syncthreads();
#pragma unroll
    for (int i = 0; i < 4; ++i)
        wT[(long)(n0 + ty + 8 * i) * K + k0 + tx] = (short)f2b_bits(tile[tx][ty + 8 * i]);
}

// ---------------- GEMM: C = A @ Bt^T + bias ----------------
// MODE 0: qkv epilogue — cols<1024 bf16*QSCALE, cols[1024,2048) bf16, cols>=2048 -> vt transposed
// MODE 1: f32 out + bias
template<int MODE>
__global__ __launch_bounds__(256, 2) void gemm_bt(const short* __restrict__ A,
                                                  const short* __restrict__ Bt,
                                                  const float* __restrict__ bias,
                                                  void* __restrict__ Cv,
                                                  short* __restrict__ vtp,
                                                  int M, int N, int K) {
    __shared__ __align__(16) short lsA[128 * 32];
    __shared__ __align__(16) short lsB[128 * 32];
    const int tid = threadIdx.x;
    const int lane = tid & 63;
    const int w = tid >> 6;
    const int wr = w >> 1, wc = w & 1;
    const int l15 = lane & 15, lg = lane >> 4;
    const long m0 = (long)blockIdx.y * 128;
    const long n0 = (long)blockIdx.x * 128;

    f32x4_t acc[4][4] = {};

    const int srow = tid >> 2;
    const int scol = (tid & 3) * 8;
    const short* gA = A + (m0 + srow) * (long)K + scol;
    const short* gB = Bt + (n0 + srow) * (long)K + scol;
    short* lA = lsA + tid * 8;
    short* lB = lsB + tid * 8;

    for (int kt = 0; kt < K; kt += 32) {
        __syncthreads();
        gload16(gA + kt, lA);
        gload16(gA + kt + (long)64 * K, lA + 2048);
        gload16(gB + kt, lB);
        gload16(gB + kt + (long)64 * K, lB + 2048);
        __syncthreads();
        bf16x8_t af[4], bfr[4];
#pragma unroll
        for (int m = 0; m < 4; ++m)
            af[m] = *(const bf16x8_t*)&lsA[(wr * 64 + m * 16 + l15) * 32 + lg * 8];
#pragma unroll
        for (int n = 0; n < 4; ++n)
            bfr[n] = *(const bf16x8_t*)&lsB[(wc * 64 + n * 16 + l15) * 32 + lg * 8];
#pragma unroll
        for (int m = 0; m < 4; ++m)
#pragma unroll
            for (int n = 0; n < 4; ++n)
                acc[m][n] = __builtin_amdgcn_mfma_f32_16x16x32_bf16(af[m], bfr[n], acc[m][n], 0, 0, 0);
    }

#pragma unroll
    for (int n = 0; n < 4; ++n) {
        const int col = (int)n0 + wc * 64 + n * 16 + l15;
        const float bv = bias[col];
        if (MODE == 1) {
#pragma unroll
            for (int m = 0; m < 4; ++m) {
                const long row = m0 + wr * 64 + m * 16 + lg * 4;
#pragma unroll
                for (int j = 0; j < 4; ++j)
                    ((float*)Cv)[(row + j) * N + col] = acc[m][n][j] + bv;
            }
        } else if (col < 2048) {
            const float sc = (col < 1024) ? QSCALE : 1.0f;
#pragma unroll
            for (int m = 0; m < 4; ++m) {
                const long row = m0 + wr * 64 + m * 16 + lg * 4;
#pragma unroll
                for (int j = 0; j < 4; ++j)
                    ((short*)Cv)[(row + j) * N + col] = (short)f2b_bits((acc[m][n][j] + bv) * sc);
            }
        } else {
            const int hc = col - 2048;
            const int hh = hc >> 6, dd = hc & 63;
#pragma unroll
            for (int m = 0; m < 4; ++m) {
                const long row = m0 + wr * 64 + m * 16 + lg * 4;
                const int bb = (int)(row >> 11), tt = (int)(row & 2047);
                s16x4_t pk;
#pragma unroll
                for (int j = 0; j < 4; ++j) pk[j] = (short)f2b_bits(acc[m][n][j] + bv);
                *(s16x4_t*)&vtp[((long)(bb * 16 + hh) * 64 + dd) * 2048 + tt] = pk;
            }
        }
    }
}

// ---------------- causal flash attention ----------------
// q-tile 128 (4 waves x QBLK=32), kv-tile 64, 512 blocks (2/CU), per-CU work sum = 34 tiles
__global__ __launch_bounds__(256, 2) void attn_fwd(const short* __restrict__ qkv,
                                                   const short* __restrict__ vt,
                                                   short* __restrict__ y) {
    __shared__ __align__(16) short lsK[2][64 * 64];
    __shared__ __align__(16) short lsV[2][64 * 64];
    __shared__ __align__(16) short lsP[4 * 32 * 64];
    const int bid = blockIdx.x;
    const int bh = bid & 31;
    const int t = bid >> 5;
    const int qi = (t < 8) ? (15 - 2 * t) : (2 * (t - 8));   // per-CU pair sums to 34 iters
    const int iters = 2 * qi + 2;
    const int b = bh >> 4, h = bh & 15;
    const int tid = threadIdx.x, w = tid >> 6, lane = tid & 63;
    const int l15 = lane & 15, lg = lane >> 4, lg4 = lg * 4;
    const int swz = (l15 & 7) << 4;

    const int qmin = qi * 128 + w * 32;

    bf16x8_t qf[2][2];
#pragma unroll
    for (int qq = 0; qq < 2; ++qq)
#pragma unroll
        for (int kq = 0; kq < 2; ++kq)
            qf[qq][kq] = *(const bf16x8_t*)&qkv[((long)b * 2048 + qmin + qq * 16 + l15) * 3072 +
                                                h * 64 + kq * 32 + lg * 8];

    const int srow = tid >> 3;
    const int scolb = (tid & 7) * 16;
    const int sc = (scolb ^ ((srow & 7) << 4)) >> 1;
    const short* gK = qkv + ((long)b * 2048 + srow) * 3072 + 1024 + h * 64 + sc;
    const short* gV = vt + ((long)bh * 64 + srow) * 2048 + sc;

    auto STAGE = [&](int jt, int bufi) {
        const short* k0 = gK + (long)jt * 64 * 3072;
        const short* v0 = gV + (long)jt * 64;
        gload16(k0,             &lsK[bufi][tid * 8]);
        gload16(k0 + 32 * 3072, &lsK[bufi][tid * 8 + 2048]);
        gload16(v0,             &lsV[bufi][tid * 8]);
        gload16(v0 + 32 * 2048, &lsV[bufi][tid * 8 + 2048]);
    };

    float mrow[2] = {-3e38f, -3e38f}, lrow[2] = {0.f, 0.f};
    f32x4_t oacc[2][4] = {};

    STAGE(0, 0);
    __syncthreads();
    int buf = 0;

    for (int j = 0; j < iters; ++j) {
        if (j + 1 < iters) STAGE(j + 1, buf ^ 1);
        const int kv0 = j * 64;
        if (kv0 <= qmin + 31) {
            const char* Kb = (const char*)lsK[buf];
            const char* Vb = (const char*)lsV[buf];
            const int base0 = qmin - kv0;
            const bool needmask = (base0 < 63);
            int nlim0 = 4, nlim1 = 4;
            if (needmask) {
                nlim0 = min(4, ((base0 + 15) >> 4) + 1);
                nlim1 = min(4, ((base0 + 31) >> 4) + 1);
            }

            // S^T = K * Q^T ; col = q (l15), row = kv (n*16+lg4+r)
            f32x4_t s[2][4] = {};
#pragma unroll
            for (int kq = 0; kq < 2; ++kq)
#pragma unroll
                for (int n = 0; n < 4; ++n)
                    if (n < nlim1) {
                        bf16x8_t kf = *(const bf16x8_t*)(Kb + (n * 16 + l15) * 128 +
                                                         ((kq * 64 + lg * 16) ^ swz));
                        s[1][n] = __builtin_amdgcn_mfma_f32_16x16x32_bf16(kf, qf[1][kq], s[1][n], 0, 0, 0);
                        if (n < nlim0)
                            s[0][n] = __builtin_amdgcn_mfma_f32_16x16x32_bf16(kf, qf[0][kq], s[0][n], 0, 0, 0);
                    }

            float p[2][4][4];
#pragma unroll
            for (int qq = 0; qq < 2; ++qq)
#pragma unroll
                for (int n = 0; n < 4; ++n)
#pragma unroll
                    for (int r = 0; r < 4; ++r) p[qq][n][r] = s[qq][n][r];

            if (needmask) {
#pragma unroll
                for (int qq = 0; qq < 2; ++qq) {
                    const int qb = base0 + qq * 16 + l15;
#pragma unroll
                    for (int n = 0; n < 4; ++n)
#pragma unroll
                        for (int r = 0; r < 4; ++r)
                            if (n * 16 + lg4 + r > qb) p[qq][n][r] = -3e38f;
                }
            }

            float pm[2];
#pragma unroll
            for (int qq = 0; qq < 2; ++qq) {
                float v = -3e38f;
#pragma unroll
                for (int n = 0; n < 4; ++n)
                    v = fmaxf(v, fmaxf(fmaxf(p[qq][n][0], p[qq][n][1]),
                                       fmaxf(p[qq][n][2], p[qq][n][3])));
                v = fmaxf(v, __shfl_xor(v, 16));
                v = fmaxf(v, __shfl_xor(v, 32));
                pm[qq] = v;
            }

            // defer-max (T13): only rescale when max grew by > 8 (log2 units)
            if (!__all((pm[0] <= mrow[0] + 8.f) && (pm[1] <= mrow[1] + 8.f))) {
#pragma unroll
                for (int qq = 0; qq < 2; ++qq) {
                    const float mnew = fmaxf(mrow[qq], pm[qq]);
                    const float al = EXP2F(mrow[qq] - mnew);
                    mrow[qq] = mnew;
                    lrow[qq] *= al;
                    float ar[4];
#pragma unroll
                    for (int r = 0; r < 4; ++r) ar[r] = __shfl(al, lg4 + r);
#pragma unroll
                    for (int n = 0; n < 4; ++n)
#pragma unroll
                        for (int r = 0; r < 4; ++r) oacc[qq][n][r] *= ar[r];
                }
            }

#pragma unroll
            for (int qq = 0; qq < 2; ++qq) {
                float lsum = 0.f;
                char* Pb = (char*)lsP + w * 4096 + (qq * 16 + l15) * 128;
#pragma unroll
                for (int n = 0; n < 4; ++n) {
#pragma unroll
                    for (int r = 0; r < 4; ++r) {
                        const float pv = EXP2F(p[qq][n][r] - mrow[qq]);
                        lsum += pv;
                        p[qq][n][r] = pv;
                    }
                    u32x2_t dw;
                    dw[0] = cvtpk_bf16(p[qq][n][0], p[qq][n][1]);
                    dw[1] = cvtpk_bf16(p[qq][n][2], p[qq][n][3]);
                    *(u32x2_t*)(Pb + ((n * 32 + lg * 8) ^ swz)) = dw;
                }
                lsum += __shfl_xor(lsum, 16);
                lsum += __shfl_xor(lsum, 32);
                lrow[qq] += lsum;
            }

            asm volatile("s_waitcnt lgkmcnt(0)" ::: "memory");

            // O += P V
#pragma unroll
            for (int kk = 0; kk < 2; ++kk) {
                if (kv0 + kk * 32 <= qmin + 31) {
                    bf16x8_t pf0 = *(const bf16x8_t*)((char*)lsP + w * 4096 + l15 * 128 +
                                                      ((kk * 64 + lg * 16) ^ swz));
                    bf16x8_t pf1 = *(const bf16x8_t*)((char*)lsP + w * 4096 + (16 + l15) * 128 +
                                                      ((kk * 64 + lg * 16) ^ swz));
#pragma unroll
                    for (int n = 0; n < 4; ++n) {
                        bf16x8_t vf = *(const bf16x8_t*)(Vb + (n * 16 + l15) * 128 +
                                                         ((kk * 64 + lg * 16) ^ swz));
                        oacc[0][n] = __builtin_amdgcn_mfma_f32_16x16x32_bf16(pf0, vf, oacc[0][n], 0, 0, 0);
                        oacc[1][n] = __builtin_amdgcn_mfma_f32_16x16x32_bf16(pf1, vf, oacc[1][n], 0, 0, 0);
                    }
                }
            }
        }
        __syncthreads();
        buf ^= 1;
    }

#pragma unroll
    for (int qq = 0; qq < 2; ++qq) {
        float lr[4];
#pragma unroll
        for (int r = 0; r < 4; ++r) lr[r] = 1.0f / __shfl(lrow[qq], lg4 + r);
#pragma unroll
        for (int n = 0; n < 4; ++n)
#pragma unroll
            for (int r = 0; r < 4; ++r)
                y[((long)b * 2048 + qmin + qq * 16 + lg4 + r) * 1024 + h * 64 + n * 16 + l15] =
                    (short)f2b_bits(oacc[qq][n][r] * lr[r]);
    }
}

extern "C" void kernel_launch(void* const* d_in, const int* in_sizes, int n_in,
                              void* d_out, int out_size, void* d_ws, size_t ws_size,
                              hipStream_t stream) {
    const float* x     = (const float*)d_in[0];
    const float* w_qkv = (const float*)d_in[1];
    const float* b_qkv = (const float*)d_in[2];
    const float* w_out = (const float*)d_in[3];
    const float* b_out = (const float*)d_in[4];

    char* ws = (char*)d_ws;
    size_t off = 0;
    short* xb    = (short*)(ws + off); off += (size_t)4096 * 1024 * 2;
    short* wqkvT = (short*)(ws + off); off += (size_t)3072 * 1024 * 2;
    short* woutT = (short*)(ws + off); off += (size_t)1024 * 1024 * 2;
    short* qkvb  = (short*)(ws + off); off += (size_t)4096 * 3072 * 2;
    short* vt    = (short*)(ws + off); off += (size_t)32 * 64 * 2048 * 2;
    short* yatt  = (short*)(ws + off); off += (size_t)4096 * 1024 * 2;

    cast_bf16_k<<<4096, 256, 0, stream>>>(x, xb, 4194304L);
    transpose_cast<<<dim3(96, 32), dim3(32, 8), 0, stream>>>(w_qkv, wqkvT, 1024, 3072);
    transpose_cast<<<dim3(32, 32), dim3(32, 8), 0, stream>>>(w_out, woutT, 1024, 1024);
    gemm_bt<0><<<dim3(24, 32), 256, 0, stream>>>(xb, wqkvT, b_qkv, (void*)qkvb, vt, 4096, 3072, 1024);
    attn_fwd<<<512, 256, 0, stream>>>(qkvb, vt, yatt);
    gemm_bt<1><<<dim3(8, 32), 256, 0, stream>>>(yatt, woutT, b_out, d_out, nullptr, 4096, 1024, 1024);
}

// Round 4
// 188.288 us; speedup vs baseline: 1.0974x; 1.0974x over previous
//
#include <hip/hip_runtime.h>
#include <hip/hip_bf16.h>

#define DEVI __device__ __forceinline__

typedef __attribute__((ext_vector_type(8))) short bf16x8_t;
typedef __attribute__((ext_vector_type(4))) float f32x4_t;
typedef __attribute__((ext_vector_type(4))) short s16x4_t;
typedef __attribute__((ext_vector_type(2))) unsigned int u32x2_t;

#define QSCALE 0.18033688011112043f   /* 0.125 * log2(e): softmax in exp2 domain */
#define EXP2F(x) __builtin_amdgcn_exp2f(x)

// fp32 -> bf16 bits, round-to-nearest-even
static DEVI unsigned short f2b_bits(float f) {
    unsigned int u = __float_as_uint(f);
    unsigned int r = (u + 0x7fffu + ((u >> 16) & 1u)) >> 16;
    return (unsigned short)r;
}

static DEVI unsigned int cvtpk_bf16(float lo, float hi) {
    unsigned int r;
    asm("v_cvt_pk_bf16_f32 %0, %1, %2" : "=v"(r) : "v"(lo), "v"(hi));
    return r;
}

static DEVI void gload16(const short* g, short* l) {
    __builtin_amdgcn_global_load_lds((const __attribute__((address_space(1))) void*)g,
                                     (__attribute__((address_space(3))) void*)l, 16, 0, 0);
}

// ---------------- cast fp32 -> bf16 ----------------
__global__ void cast_bf16_k(const float* __restrict__ in, short* __restrict__ out, long n) {
    long i = ((long)blockIdx.x * blockDim.x + threadIdx.x) * 4;
    if (i >= n) return;
    const float4 v = *(const float4*)(in + i);
    s16x4_t o;
    o[0] = (short)f2b_bits(v.x); o[1] = (short)f2b_bits(v.y);
    o[2] = (short)f2b_bits(v.z); o[3] = (short)f2b_bits(v.w);
    *(s16x4_t*)(out + i) = o;
}

// ---------------- transpose + cast: w[K][N] fp32 -> wT[N][K] bf16 ----------------
__global__ void transpose_cast(const float* __restrict__ w, short* __restrict__ wT,
                               int K, int N) {
    __shared__ float tile[32][33];
    const int n0 = blockIdx.x * 32, k0 = blockIdx.y * 32;
    const int tx = threadIdx.x, ty = threadIdx.y;
#pragma unroll
    for (int i = 0; i < 4; ++i)
        tile[ty + 8 * i][tx] = w[(long)(k0 + ty + 8 * i) * N + n0 + tx];
    __syncthreads();
#pragma unroll
    for (int i = 0; i < 4; ++i)
        wT[(long)(n0 + ty + 8 * i) * K + k0 + tx] = (short)f2b_bits(tile[tx][ty + 8 * i]);
}

// ---------------- GEMM: C = A @ Bt^T + bias (single-barrier double-buffered K-loop) ----------------
// MODE 0: qkv epilogue — cols<1024 bf16*QSCALE, cols[1024,2048) bf16, cols>=2048 -> vt transposed
// MODE 1: f32 out + bias
template<int MODE>
__global__ __launch_bounds__(256, 2) void gemm_bt(const short* __restrict__ A,
                                                  const short* __restrict__ Bt,
                                                  const float* __restrict__ bias,
                                                  void* __restrict__ Cv,
                                                  short* __restrict__ vtp,
                                                  int M, int N, int K) {
    __shared__ __align__(16) short lsA[2][128 * 32];
    __shared__ __align__(16) short lsB[2][128 * 32];
    const int tid = threadIdx.x;
    const int lane = tid & 63;
    const int w = tid >> 6;
    const int wr = w >> 1, wc = w & 1;
    const int l15 = lane & 15, lg = lane >> 4;
    const long m0 = (long)blockIdx.y * 128;
    const long n0 = (long)blockIdx.x * 128;

    f32x4_t acc[4][4] = {};

    const int srow = tid >> 2;
    const int scol = (tid & 3) * 8;
    const short* gA = A + (m0 + srow) * (long)K + scol;
    const short* gB = Bt + (n0 + srow) * (long)K + scol;

    auto STAGE = [&](int kt, int bi) {
        gload16(gA + kt,                &lsA[bi][tid * 8]);
        gload16(gA + kt + (long)64 * K, &lsA[bi][tid * 8 + 2048]);
        gload16(gB + kt,                &lsB[bi][tid * 8]);
        gload16(gB + kt + (long)64 * K, &lsB[bi][tid * 8 + 2048]);
    };

    const int nt = K >> 5;
    STAGE(0, 0);
    __syncthreads();
    int buf = 0;

    for (int i = 0; i < nt; ++i) {
        if (i + 1 < nt) STAGE((i + 1) << 5, buf ^ 1);
        bf16x8_t af[4], bfr[4];
#pragma unroll
        for (int m = 0; m < 4; ++m)
            af[m] = *(const bf16x8_t*)&lsA[buf][(wr * 64 + m * 16 + l15) * 32 + lg * 8];
#pragma unroll
        for (int n = 0; n < 4; ++n)
            bfr[n] = *(const bf16x8_t*)&lsB[buf][(wc * 64 + n * 16 + l15) * 32 + lg * 8];
        __builtin_amdgcn_s_setprio(1);
#pragma unroll
        for (int m = 0; m < 4; ++m)
#pragma unroll
            for (int n = 0; n < 4; ++n)
                acc[m][n] = __builtin_amdgcn_mfma_f32_16x16x32_bf16(af[m], bfr[n], acc[m][n], 0, 0, 0);
        __builtin_amdgcn_s_setprio(0);
        __syncthreads();
        buf ^= 1;
    }

#pragma unroll
    for (int n = 0; n < 4; ++n) {
        const int col = (int)n0 + wc * 64 + n * 16 + l15;
        const float bv = bias[col];
        if (MODE == 1) {
#pragma unroll
            for (int m = 0; m < 4; ++m) {
                const long row = m0 + wr * 64 + m * 16 + lg * 4;
#pragma unroll
                for (int j = 0; j < 4; ++j)
                    ((float*)Cv)[(row + j) * N + col] = acc[m][n][j] + bv;
            }
        } else if (col < 2048) {
            const float sc = (col < 1024) ? QSCALE : 1.0f;
#pragma unroll
            for (int m = 0; m < 4; ++m) {
                const long row = m0 + wr * 64 + m * 16 + lg * 4;
#pragma unroll
                for (int j = 0; j < 4; ++j)
                    ((short*)Cv)[(row + j) * N + col] = (short)f2b_bits((acc[m][n][j] + bv) * sc);
            }
        } else {
            const int hc = col - 2048;
            const int hh = hc >> 6, dd = hc & 63;
#pragma unroll
            for (int m = 0; m < 4; ++m) {
                const long row = m0 + wr * 64 + m * 16 + lg * 4;
                const int bb = (int)(row >> 11), tt = (int)(row & 2047);
                s16x4_t pk;
#pragma unroll
                for (int j = 0; j < 4; ++j) pk[j] = (short)f2b_bits(acc[m][n][j] + bv);
                *(s16x4_t*)&vtp[((long)(bb * 16 + hh) * 64 + dd) * 2048 + tt] = pk;
            }
        }
    }
}

// ---------------- causal flash attention (R2 structure + exp2/defer-max/setprio) ----------------
// grid: 1024 blocks; bh = bid&31, t = bid>>5, qi = t<16 ? t : 47-t (per-CU work-sum = 66)
// 4 waves x 16 q-rows; KV tile 64; K/V double-buffered LDS, XOR-swizzled
__global__ __launch_bounds__(256, 4) void attn_fwd(const short* __restrict__ qkv,
                                                   const short* __restrict__ vt,
                                                   short* __restrict__ y) {
    __shared__ __align__(16) short lsK[2][64 * 64];
    __shared__ __align__(16) short lsV[2][64 * 64];
    __shared__ __align__(16) short lsP[4 * 16 * 64];
    const int bid = blockIdx.x;
    const int bh = bid & 31;
    const int t = bid >> 5;
    const int qi = (t < 16) ? t : 47 - t;
    const int b = bh >> 4, h = bh & 15;
    const int tid = threadIdx.x, w = tid >> 6, lane = tid & 63;
    const int l15 = lane & 15, lg = lane >> 4;
    const int lg4 = lg * 4;
    const int swz = (l15 & 7) << 4;

    // Q fragments (B operand) — pre-scaled by 0.125*log2e in GEMM epilogue
    const long qrow = (long)qi * 64 + w * 16 + l15;
    const bf16x8_t qf0 = *(const bf16x8_t*)&qkv[((long)b * 2048 + qrow) * 3072 + h * 64 + lg * 8];
    const bf16x8_t qf1 = *(const bf16x8_t*)&qkv[((long)b * 2048 + qrow) * 3072 + h * 64 + 32 + lg * 8];

    const int srow = tid >> 3;
    const int scolb = (tid & 7) * 16;
    const int sc = (scolb ^ ((srow & 7) << 4)) >> 1;
    const short* gK = qkv + ((long)b * 2048 + srow) * 3072 + 1024 + h * 64 + sc;
    const short* gV = vt + ((long)bh * 64 + srow) * 2048 + sc;

    auto STAGE = [&](int jt, int bufi) {
        const short* k0 = gK + (long)jt * 64 * 3072;
        const short* v0 = gV + (long)jt * 64;
        gload16(k0,             &lsK[bufi][tid * 8]);
        gload16(k0 + 32 * 3072, &lsK[bufi][tid * 8 + 2048]);
        gload16(v0,             &lsV[bufi][tid * 8]);
        gload16(v0 + 32 * 2048, &lsV[bufi][tid * 8 + 2048]);
    };

    float mrow = -3e38f, lrow = 0.f;
    f32x4_t oacc[4] = {};

    STAGE(0, 0);
    __syncthreads();
    int buf = 0;

    for (int j = 0; j <= qi; ++j) {
        if (j < qi) STAGE(j + 1, buf ^ 1);
        const bool diag = (j == qi);
        const char* Kb = (const char*)lsK[buf];
        const char* Vb = (const char*)lsV[buf];

        // S^T = K * Q^T : col = q = l15, row = kv = n*16 + lg4 + r
        f32x4_t s[4] = {};
        const int nlim = diag ? (w + 1) : 4;
        __builtin_amdgcn_s_setprio(1);
#pragma unroll
        for (int kq = 0; kq < 2; ++kq) {
            const bf16x8_t qf = kq ? qf1 : qf0;
#pragma unroll
            for (int n = 0; n < 4; ++n) {
                if (n < nlim) {
                    bf16x8_t kf = *(const bf16x8_t*)(Kb + (n * 16 + l15) * 128 + ((kq * 64 + lg * 16) ^ swz));
                    s[n] = __builtin_amdgcn_mfma_f32_16x16x32_bf16(kf, qf, s[n], 0, 0, 0);
                }
            }
        }
        __builtin_amdgcn_s_setprio(0);

        float p[4][4];
#pragma unroll
        for (int n = 0; n < 4; ++n)
#pragma unroll
            for (int r = 0; r < 4; ++r) p[n][r] = s[n][r];

        if (diag) {
            const int ql = w * 16 + l15 - lg4;
#pragma unroll
            for (int n = 0; n < 4; ++n)
#pragma unroll
                for (int r = 0; r < 4; ++r)
                    if (n * 16 + r > ql) p[n][r] = -3e38f;
        }

        float pm = -3e38f;
#pragma unroll
        for (int n = 0; n < 4; ++n)
            pm = fmaxf(pm, fmaxf(fmaxf(p[n][0], p[n][1]), fmaxf(p[n][2], p[n][3])));
        pm = fmaxf(pm, __shfl_xor(pm, 16));
        pm = fmaxf(pm, __shfl_xor(pm, 32));

        // defer-max (T13): rescale only when max grew by > 8 (log2 units)
        if (!__all(pm <= mrow + 8.f)) {
            const float mnew = fmaxf(mrow, pm);
            const float al = EXP2F(mrow - mnew);
            mrow = mnew;
            lrow *= al;
            float ar[4];
#pragma unroll
            for (int r = 0; r < 4; ++r) ar[r] = __shfl(al, lg4 + r);
#pragma unroll
            for (int n = 0; n < 4; ++n)
#pragma unroll
                for (int r = 0; r < 4; ++r) oacc[n][r] *= ar[r];
        }

        float lsum = 0.f;
        char* Pb = (char*)lsP + w * 2048 + l15 * 128;
#pragma unroll
        for (int n = 0; n < 4; ++n) {
#pragma unroll
            for (int r = 0; r < 4; ++r) {
                p[n][r] = EXP2F(p[n][r] - mrow);
                lsum += p[n][r];
            }
            u32x2_t dw;
            dw[0] = cvtpk_bf16(p[n][0], p[n][1]);
            dw[1] = cvtpk_bf16(p[n][2], p[n][3]);
            *(u32x2_t*)(Pb + ((n * 32 + lg * 8) ^ swz)) = dw;
        }
        lsum += __shfl_xor(lsum, 16);
        lsum += __shfl_xor(lsum, 32);
        lrow += lsum;

        asm volatile("s_waitcnt lgkmcnt(0)" ::: "memory");   // P writes visible (wave-local)

        // O += P V
        __builtin_amdgcn_s_setprio(1);
#pragma unroll
        for (int kk = 0; kk < 2; ++kk) {
            if (!(diag && kk * 32 > w * 16 + 15)) {
                bf16x8_t pf = *(const bf16x8_t*)(Pb + ((kk * 64 + lg * 16) ^ swz));
#pragma unroll
                for (int n = 0; n < 4; ++n) {
                    bf16x8_t vf = *(const bf16x8_t*)(Vb + (n * 16 + l15) * 128 + ((kk * 64 + lg * 16) ^ swz));
                    oacc[n] = __builtin_amdgcn_mfma_f32_16x16x32_bf16(pf, vf, oacc[n], 0, 0, 0);
                }
            }
        }
        __builtin_amdgcn_s_setprio(0);
        __syncthreads();
        buf ^= 1;
    }

    float lr[4];
#pragma unroll
    for (int r = 0; r < 4; ++r) lr[r] = 1.0f / __shfl(lrow, lg4 + r);
#pragma unroll
    for (int n = 0; n < 4; ++n)
#pragma unroll
        for (int r = 0; r < 4; ++r) {
            const float ov = oacc[n][r] * lr[r];
            y[((long)b * 2048 + qi * 64 + w * 16 + lg4 + r) * 1024 + h * 64 + n * 16 + l15] =
                (short)f2b_bits(ov);
        }
}

extern "C" void kernel_launch(void* const* d_in, const int* in_sizes, int n_in,
                              void* d_out, int out_size, void* d_ws, size_t ws_size,
                              hipStream_t stream) {
    const float* x     = (const float*)d_in[0];
    const float* w_qkv = (const float*)d_in[1];
    const float* b_qkv = (const float*)d_in[2];
    const float* w_out = (const float*)d_in[3];
    const float* b_out = (const float*)d_in[4];

    char* ws = (char*)d_ws;
    size_t off = 0;
    short* xb    = (short*)(ws + off); off += (size_t)4096 * 1024 * 2;
    short* wqkvT = (short*)(ws + off); off += (size_t)3072 * 1024 * 2;
    short* woutT = (short*)(ws + off); off += (size_t)1024 * 1024 * 2;
    short* qkvb  = (short*)(ws + off); off += (size_t)4096 * 3072 * 2;
    short* vt    = (short*)(ws + off); off += (size_t)32 * 64 * 2048 * 2;
    short* yatt  = (short*)(ws + off); off += (size_t)4096 * 1024 * 2;

    cast_bf16_k<<<4096, 256, 0, stream>>>(x, xb, 4194304L);
    transpose_cast<<<dim3(96, 32), dim3(32, 8), 0, stream>>>(w_qkv, wqkvT, 1024, 3072);
    transpose_cast<<<dim3(32, 32), dim3(32, 8), 0, stream>>>(w_out, woutT, 1024, 1024);
    gemm_bt<0><<<dim3(24, 32), 256, 0, stream>>>(xb, wqkvT, b_qkv, (void*)qkvb, vt, 4096, 3072, 1024);
    attn_fwd<<<1024, 256, 0, stream>>>(qkvb, vt, yatt);
    gemm_bt<1><<<dim3(8, 32), 256, 0, stream>>>(yatt, woutT, b_out, d_out, nullptr, 4096, 1024, 1024);
}

// Round 5
// 179.412 us; speedup vs baseline: 1.1517x; 1.0495x over previous
//
#include <hip/hip_runtime.h>
#include <hip/hip_bf16.h>

#define DEVI __device__ __forceinline__

typedef __attribute__((ext_vector_type(8))) short bf16x8_t;
typedef __attribute__((ext_vector_type(4))) float f32x4_t;
typedef __attribute__((ext_vector_type(4))) short s16x4_t;
typedef __attribute__((ext_vector_type(2))) unsigned int u32x2_t;

#define QSCALE 0.18033688011112043f   /* 0.125 * log2(e): softmax in exp2 domain */
#define EXP2F(x) __builtin_amdgcn_exp2f(x)

// fp32 -> bf16 bits, round-to-nearest-even
static DEVI unsigned short f2b_bits(float f) {
    unsigned int u = __float_as_uint(f);
    unsigned int r = (u + 0x7fffu + ((u >> 16) & 1u)) >> 16;
    return (unsigned short)r;
}

static DEVI unsigned int cvtpk_bf16(float lo, float hi) {
    unsigned int r;
    asm("v_cvt_pk_bf16_f32 %0, %1, %2" : "=v"(r) : "v"(lo), "v"(hi));
    return r;
}

static DEVI void gload16(const short* g, short* l) {
    __builtin_amdgcn_global_load_lds((const __attribute__((address_space(1))) void*)g,
                                     (__attribute__((address_space(3))) void*)l, 16, 0, 0);
}

#define MEMFENCE asm volatile("" ::: "memory")

// ---------------- fused prep: cast x, transpose+cast w_qkv and w_out ----------------
__global__ __launch_bounds__(256) void prep_k(const float* __restrict__ x, short* __restrict__ xb,
                                              const float* __restrict__ wqkv, short* __restrict__ wqkvT,
                                              const float* __restrict__ wout, short* __restrict__ woutT) {
    const int bid = blockIdx.x;
    const int tid = threadIdx.x;
    if (bid < 4096) {
        const long i = ((long)bid * 256 + tid) * 4;
        const float4 v = *(const float4*)(x + i);
        s16x4_t o;
        o[0] = (short)f2b_bits(v.x); o[1] = (short)f2b_bits(v.y);
        o[2] = (short)f2b_bits(v.z); o[3] = (short)f2b_bits(v.w);
        *(s16x4_t*)(xb + i) = o;
        return;
    }
    __shared__ float tile[32][33];
    const float* w; short* wT; int K, N, bx, by;
    if (bid < 4096 + 3072) {
        const int rel = bid - 4096;
        w = wqkv; wT = wqkvT; K = 1024; N = 3072; bx = rel % 96; by = rel / 96;
    } else {
        const int rel = bid - 7168;
        w = wout; wT = woutT; K = 1024; N = 1024; bx = rel & 31; by = rel >> 5;
    }
    const int n0 = bx * 32, k0 = by * 32;
    const int tx = tid & 31, ty = tid >> 5;
#pragma unroll
    for (int i = 0; i < 4; ++i)
        tile[ty + 8 * i][tx] = w[(long)(k0 + ty + 8 * i) * N + n0 + tx];
    __syncthreads();
#pragma unroll
    for (int i = 0; i < 4; ++i)
        wT[(long)(n0 + ty + 8 * i) * K + k0 + tx] = (short)f2b_bits(tile[tx][ty + 8 * i]);
}

// ---------------- GEMM: C[M][BNtot] = A @ Bt^T + bias; counted-vmcnt 2-phase pipeline ----------
// NF = n-fragments per wave; tile = 128 x (32*NF). MODE 0: qkv epilogue (NF=4). MODE 1: f32 (NF=2).
template<int MODE, int NF>
__global__ __launch_bounds__(256, 3) void gemm_bt(const short* __restrict__ A,
                                                  const short* __restrict__ Bt,
                                                  const float* __restrict__ bias,
                                                  void* __restrict__ Cv,
                                                  short* __restrict__ vtp,
                                                  int M, int N, int K) {
    __shared__ __align__(16) short lsA[2][128 * 32];
    __shared__ __align__(16) short lsB[2][32 * NF * 32];
    const int tid = threadIdx.x;
    const int lane = tid & 63;
    const int w = tid >> 6;
    const int wr = w >> 1, wc = w & 1;
    const int l15 = lane & 15, lg = lane >> 4;
    const long m0 = (long)blockIdx.y * 128;
    const long n0 = (long)blockIdx.x * (32 * NF);

    f32x4_t acc[4][NF] = {};

    const int srow = tid >> 2;
    const int scol = (tid & 3) * 8;
    const short* gA = A + (m0 + srow) * (long)K + scol;
    const short* gB = Bt + (n0 + srow) * (long)K + scol;

    auto STAGE = [&](int kt, int bi) {
        gload16(gA + kt,                &lsA[bi][tid * 8]);
        gload16(gA + kt + (long)64 * K, &lsA[bi][tid * 8 + 2048]);
        gload16(gB + kt,                &lsB[bi][tid * 8]);
        if (NF == 4) gload16(gB + kt + (long)64 * K, &lsB[bi][tid * 8 + 2048]);
    };

    const int nt = K >> 5;
    STAGE(0, 0);
    int buf = 0;

    for (int i = 0; i < nt; ++i) {
        if (i + 1 < nt) {
            STAGE((i + 1) << 5, buf ^ 1);
            if (NF == 4) asm volatile("s_waitcnt vmcnt(4)" ::: "memory");
            else         asm volatile("s_waitcnt vmcnt(3)" ::: "memory");
        } else {
            asm volatile("s_waitcnt vmcnt(0)" ::: "memory");
        }
        __builtin_amdgcn_s_barrier();
        MEMFENCE;
        bf16x8_t af[4], bfr[NF];
#pragma unroll
        for (int m = 0; m < 4; ++m)
            af[m] = *(const bf16x8_t*)&lsA[buf][(wr * 64 + m * 16 + l15) * 32 + lg * 8];
#pragma unroll
        for (int n = 0; n < NF; ++n)
            bfr[n] = *(const bf16x8_t*)&lsB[buf][(wc * NF * 16 + n * 16 + l15) * 32 + lg * 8];
#pragma unroll
        for (int m = 0; m < 4; ++m)
#pragma unroll
            for (int n = 0; n < NF; ++n)
                acc[m][n] = __builtin_amdgcn_mfma_f32_16x16x32_bf16(af[m], bfr[n], acc[m][n], 0, 0, 0);
        MEMFENCE;
        __builtin_amdgcn_s_barrier();
        buf ^= 1;
    }

#pragma unroll
    for (int n = 0; n < NF; ++n) {
        const int col = (int)n0 + wc * NF * 16 + n * 16 + l15;
        const float bv = bias[col];
        if (MODE == 1) {
#pragma unroll
            for (int m = 0; m < 4; ++m) {
                const long row = m0 + wr * 64 + m * 16 + lg * 4;
#pragma unroll
                for (int j = 0; j < 4; ++j)
                    ((float*)Cv)[(row + j) * N + col] = acc[m][n][j] + bv;
            }
        } else if (col < 2048) {
            const float sc = (col < 1024) ? QSCALE : 1.0f;
#pragma unroll
            for (int m = 0; m < 4; ++m) {
                const long row = m0 + wr * 64 + m * 16 + lg * 4;
#pragma unroll
                for (int j = 0; j < 4; ++j)
                    ((short*)Cv)[(row + j) * N + col] = (short)f2b_bits((acc[m][n][j] + bv) * sc);
            }
        } else {
            const int hc = col - 2048;
            const int hh = hc >> 6, dd = hc & 63;
#pragma unroll
            for (int m = 0; m < 4; ++m) {
                const long row = m0 + wr * 64 + m * 16 + lg * 4;
                const int bb = (int)(row >> 11), tt = (int)(row & 2047);
                s16x4_t pk;
#pragma unroll
                for (int j = 0; j < 4; ++j) pk[j] = (short)f2b_bits(acc[m][n][j] + bv);
                *(s16x4_t*)&vtp[((long)(bb * 16 + hh) * 64 + dd) * 2048 + tt] = pk;
            }
        }
    }
}

// ---------------- causal flash attention (counted-vmcnt pipeline) ----------------
// grid: 1024 blocks; bh = bid&31, t = bid>>5, qi = t<16 ? t : 47-t (per-CU work-sum balanced)
// 4 waves x 16 q-rows; KV tile 64; K/V double-buffered LDS, XOR-swizzled
__global__ __launch_bounds__(256, 4) void attn_fwd(const short* __restrict__ qkv,
                                                   const short* __restrict__ vt,
                                                   short* __restrict__ y) {
    __shared__ __align__(16) short lsK[2][64 * 64];
    __shared__ __align__(16) short lsV[2][64 * 64];
    __shared__ __align__(16) short lsP[4 * 16 * 64];
    const int bid = blockIdx.x;
    const int bh = bid & 31;
    const int t = bid >> 5;
    const int qi = (t < 16) ? t : 47 - t;
    const int b = bh >> 4, h = bh & 15;
    const int tid = threadIdx.x, w = tid >> 6, lane = tid & 63;
    const int l15 = lane & 15, lg = lane >> 4;
    const int lg4 = lg * 4;
    const int swz = (l15 & 7) << 4;

    // Q fragments (B operand) — pre-scaled by 0.125*log2e in GEMM epilogue
    const long qrow = (long)qi * 64 + w * 16 + l15;
    const bf16x8_t qf0 = *(const bf16x8_t*)&qkv[((long)b * 2048 + qrow) * 3072 + h * 64 + lg * 8];
    const bf16x8_t qf1 = *(const bf16x8_t*)&qkv[((long)b * 2048 + qrow) * 3072 + h * 64 + 32 + lg * 8];

    const int srow = tid >> 3;
    const int scolb = (tid & 7) * 16;
    const int sc = (scolb ^ ((srow & 7) << 4)) >> 1;
    const short* gK = qkv + ((long)b * 2048 + srow) * 3072 + 1024 + h * 64 + sc;
    const short* gV = vt + ((long)bh * 64 + srow) * 2048 + sc;

    auto STAGE = [&](int jt, int bufi) {
        const short* k0 = gK + (long)jt * 64 * 3072;
        const short* v0 = gV + (long)jt * 64;
        gload16(k0,             &lsK[bufi][tid * 8]);
        gload16(k0 + 32 * 3072, &lsK[bufi][tid * 8 + 2048]);
        gload16(v0,             &lsV[bufi][tid * 8]);
        gload16(v0 + 32 * 2048, &lsV[bufi][tid * 8 + 2048]);
    };

    float mrow = -3e38f, lrow = 0.f;
    f32x4_t oacc[4] = {};

    STAGE(0, 0);
    int buf = 0;

    for (int j = 0; j <= qi; ++j) {
        // counted-vmcnt (T4): keep next tile's loads in flight across the barrier
        if (j < qi) {
            STAGE(j + 1, buf ^ 1);
            asm volatile("s_waitcnt vmcnt(4)" ::: "memory");   // tile j landed (mine)
        } else {
            asm volatile("s_waitcnt vmcnt(0)" ::: "memory");
        }
        __builtin_amdgcn_s_barrier();                          // tile j landed (everyone)
        MEMFENCE;

        const bool diag = (j == qi);
        const char* Kb = (const char*)lsK[buf];
        const char* Vb = (const char*)lsV[buf];

        // S^T = K * Q^T : col = q = l15, row = kv = n*16 + lg4 + r
        f32x4_t s[4] = {};
        const int nlim = diag ? (w + 1) : 4;
        __builtin_amdgcn_s_setprio(1);
#pragma unroll
        for (int kq = 0; kq < 2; ++kq) {
            const bf16x8_t qf = kq ? qf1 : qf0;
#pragma unroll
            for (int n = 0; n < 4; ++n) {
                if (n < nlim) {
                    bf16x8_t kf = *(const bf16x8_t*)(Kb + (n * 16 + l15) * 128 + ((kq * 64 + lg * 16) ^ swz));
                    s[n] = __builtin_amdgcn_mfma_f32_16x16x32_bf16(kf, qf, s[n], 0, 0, 0);
                }
            }
        }
        __builtin_amdgcn_s_setprio(0);

        float p[4][4];
#pragma unroll
        for (int n = 0; n < 4; ++n)
#pragma unroll
            for (int r = 0; r < 4; ++r) p[n][r] = s[n][r];

        if (diag) {
            const int ql = w * 16 + l15 - lg4;
#pragma unroll
            for (int n = 0; n < 4; ++n)
#pragma unroll
                for (int r = 0; r < 4; ++r)
                    if (n * 16 + r > ql) p[n][r] = -3e38f;
        }

        float pm = -3e38f;
#pragma unroll
        for (int n = 0; n < 4; ++n)
            pm = fmaxf(pm, fmaxf(fmaxf(p[n][0], p[n][1]), fmaxf(p[n][2], p[n][3])));
        pm = fmaxf(pm, __shfl_xor(pm, 16));
        pm = fmaxf(pm, __shfl_xor(pm, 32));

        // defer-max (T13): rescale only when max grew by > 8 (log2 units)
        if (!__all(pm <= mrow + 8.f)) {
            const float mnew = fmaxf(mrow, pm);
            const float al = EXP2F(mrow - mnew);
            mrow = mnew;
            lrow *= al;
            float ar[4];
#pragma unroll
            for (int r = 0; r < 4; ++r) ar[r] = __shfl(al, lg4 + r);
#pragma unroll
            for (int n = 0; n < 4; ++n)
#pragma unroll
                for (int r = 0; r < 4; ++r) oacc[n][r] *= ar[r];
        }

        float lsum = 0.f;
        char* Pb = (char*)lsP + w * 2048 + l15 * 128;
#pragma unroll
        for (int n = 0; n < 4; ++n) {
#pragma unroll
            for (int r = 0; r < 4; ++r) {
                p[n][r] = EXP2F(p[n][r] - mrow);
                lsum += p[n][r];
            }
            u32x2_t dw;
            dw[0] = cvtpk_bf16(p[n][0], p[n][1]);
            dw[1] = cvtpk_bf16(p[n][2], p[n][3]);
            *(u32x2_t*)(Pb + ((n * 32 + lg * 8) ^ swz)) = dw;
        }
        lsum += __shfl_xor(lsum, 16);
        lsum += __shfl_xor(lsum, 32);
        lrow += lsum;

        asm volatile("s_waitcnt lgkmcnt(0)" ::: "memory");   // P writes visible (wave-local)

        // O += P V
        __builtin_amdgcn_s_setprio(1);
#pragma unroll
        for (int kk = 0; kk < 2; ++kk) {
            if (!(diag && kk * 32 > w * 16 + 15)) {
                bf16x8_t pf = *(const bf16x8_t*)(Pb + ((kk * 64 + lg * 16) ^ swz));
#pragma unroll
                for (int n = 0; n < 4; ++n) {
                    bf16x8_t vf = *(const bf16x8_t*)(Vb + (n * 16 + l15) * 128 + ((kk * 64 + lg * 16) ^ swz));
                    oacc[n] = __builtin_amdgcn_mfma_f32_16x16x32_bf16(pf, vf, oacc[n], 0, 0, 0);
                }
            }
        }
        __builtin_amdgcn_s_setprio(0);
        MEMFENCE;
        __builtin_amdgcn_s_barrier();                        // all reads of buf done
        buf ^= 1;
    }

    float lr[4];
#pragma unroll
    for (int r = 0; r < 4; ++r) lr[r] = 1.0f / __shfl(lrow, lg4 + r);
#pragma unroll
    for (int n = 0; n < 4; ++n)
#pragma unroll
        for (int r = 0; r < 4; ++r) {
            const float ov = oacc[n][r] * lr[r];
            y[((long)b * 2048 + qi * 64 + w * 16 + lg4 + r) * 1024 + h * 64 + n * 16 + l15] =
                (short)f2b_bits(ov);
        }
}

extern "C" void kernel_launch(void* const* d_in, const int* in_sizes, int n_in,
                              void* d_out, int out_size, void* d_ws, size_t ws_size,
                              hipStream_t stream) {
    const float* x     = (const float*)d_in[0];
    const float* w_qkv = (const float*)d_in[1];
    const float* b_qkv = (const float*)d_in[2];
    const float* w_out = (const float*)d_in[3];
    const float* b_out = (const float*)d_in[4];

    char* ws = (char*)d_ws;
    size_t off = 0;
    short* xb    = (short*)(ws + off); off += (size_t)4096 * 1024 * 2;
    short* wqkvT = (short*)(ws + off); off += (size_t)3072 * 1024 * 2;
    short* woutT = (short*)(ws + off); off += (size_t)1024 * 1024 * 2;
    short* qkvb  = (short*)(ws + off); off += (size_t)4096 * 3072 * 2;
    short* vt    = (short*)(ws + off); off += (size_t)32 * 64 * 2048 * 2;
    short* yatt  = (short*)(ws + off); off += (size_t)4096 * 1024 * 2;

    prep_k<<<8192, 256, 0, stream>>>(x, xb, w_qkv, wqkvT, w_out, woutT);
    gemm_bt<0, 4><<<dim3(24, 32), 256, 0, stream>>>(xb, wqkvT, b_qkv, (void*)qkvb, vt, 4096, 3072, 1024);
    attn_fwd<<<1024, 256, 0, stream>>>(qkvb, vt, yatt);
    gemm_bt<1, 2><<<dim3(16, 32), 256, 0, stream>>>(yatt, woutT, b_out, d_out, nullptr, 4096, 1024, 1024);
}